// Round 1
// baseline (1221.661 us; speedup 1.0000x reference)
//
#include <hip/hip_runtime.h>
#include <math.h>

// Problem: B=256, P=40, S=60, D=64. One workgroup per (b,p) part.
// All-fp32 baseline: fused QKV -> scores -> softmax -> PV -> FFN1(relu) ->
// FFN2(relu) -> scalar head. CDNA4 has no fp32 MFMA, so this is VALU-bound.

#define SEQ 60
#define DIM 64
#define PAD 68   // LDS row stride in floats: 272B = 17*16B (keeps float4 aligned, banks spread)

// Load W[e][d] (row-major 64x64) into LDS transposed: wt[d][e] = W[e][d].
__device__ __forceinline__ void load_wT(const float* __restrict__ W,
                                        float wt[DIM][PAD], int t) {
    #pragma unroll
    for (int r = 0; r < 16; ++r) {
        int idx = r * 256 + t;          // coalesced global read
        wt[idx & 63][idx >> 6] = W[idx];
    }
}

// C[s][e] = post(scale * sum_d A[s][d] * Bt[d][e] + bias[e])
// A: [64][PAD] row-major (K along row). Bt: [64][PAD] K-major.
// 16x16 thread grid, 4x4 register tile per thread.
template <int RELU, int TRANSC>
__device__ __forceinline__ void gemm64(const float A[DIM][PAD],
                                       const float Bt[DIM][PAD],
                                       float C[DIM][PAD],
                                       const float* __restrict__ bias,
                                       float scale, int t) {
    const int tx = t & 15, ty = t >> 4;
    const int s0 = ty * 4, e0 = tx * 4;
    float acc[4][4] = {};
    #pragma unroll 4
    for (int d = 0; d < DIM; d += 4) {
        float a[4][4], b[4][4];
        #pragma unroll
        for (int i = 0; i < 4; ++i)
            *(float4*)a[i] = *(const float4*)&A[s0 + i][d];   // 4-addr broadcast across tx
        #pragma unroll
        for (int m = 0; m < 4; ++m)
            *(float4*)b[m] = *(const float4*)&Bt[d + m][e0];  // 2-way bank alias (free)
        #pragma unroll
        for (int i = 0; i < 4; ++i)
            #pragma unroll
            for (int j = 0; j < 4; ++j)
                #pragma unroll
                for (int m = 0; m < 4; ++m)
                    acc[i][j] = fmaf(a[i][m], b[m][j], acc[i][j]);
    }
    float bj[4];
    #pragma unroll
    for (int j = 0; j < 4; ++j) bj[j] = bias ? bias[e0 + j] : 0.f;
    #pragma unroll
    for (int i = 0; i < 4; ++i)
        #pragma unroll
        for (int j = 0; j < 4; ++j) {
            float v = acc[i][j] * scale + bj[j];
            if (RELU) v = fmaxf(v, 0.f);
            if (TRANSC) C[e0 + j][s0 + i] = v;   // k stored transposed for QK^T
            else        C[s0 + i][e0 + j] = v;
        }
}

__global__ __launch_bounds__(256, 1) void fused_attn_mlp(
    const float* __restrict__ x,
    const float* __restrict__ Wq, const float* __restrict__ bq,
    const float* __restrict__ Wk, const float* __restrict__ bk,
    const float* __restrict__ Wv, const float* __restrict__ bv,
    const float* __restrict__ W1, const float* __restrict__ b1,
    const float* __restrict__ W2, const float* __restrict__ b2,
    const float* __restrict__ W3, const float* __restrict__ b3,
    float* __restrict__ out) {
    // 5 buffers x 64x68 f32 = 87 KB LDS -> 1 block/CU.
    __shared__ float xs[DIM][PAD];  // x rows (60 real + 4 zero); later: weighted (PV out)
    __shared__ float wb[DIM][PAD];  // weight^T buffer; unioned with scores/attn
    __shared__ float qs[DIM][PAD];  // q rows; later: h1
    __shared__ float kt[DIM][PAD];  // k transposed [e][s]; later: h2
    __shared__ float vs[DIM][PAD];  // v rows (K-major for PV)

    const int t = threadIdx.x;
    const int bp = blockIdx.x;
    const float* xp = x + (size_t)bp * (SEQ * DIM);

    // ---- stage x (zero-pad rows 60..63 so padded GEMM rows are benign)
    for (int idx = t; idx < SEQ * DIM; idx += 256)
        xs[idx >> 6][idx & 63] = xp[idx];
    for (int idx = SEQ * DIM + t; idx < DIM * DIM; idx += 256)
        xs[idx >> 6][idx & 63] = 0.f;

    // ---- q = x Wq^T + bq
    load_wT(Wq, wb, t);
    __syncthreads();
    gemm64<0, 0>(xs, wb, qs, bq, 1.f, t);
    __syncthreads();
    // ---- k^T
    load_wT(Wk, wb, t);
    __syncthreads();
    gemm64<0, 1>(xs, wb, kt, bk, 1.f, t);
    __syncthreads();
    // ---- v
    load_wT(Wv, wb, t);
    __syncthreads();
    gemm64<0, 0>(xs, wb, vs, bv, 1.f, t);
    __syncthreads();

    // ---- scores[i][j] = (q k^T)/8 into wb (weight buffer dead until W1)
    gemm64<0, 0>(qs, kt, wb, nullptr, 0.125f, t);
    __syncthreads();

    // ---- softmax rows 0..59, lane = column; pad cols 60..63 -> 0
    {
        const int wave = t >> 6, lane = t & 63;
        for (int i = wave; i < SEQ; i += 4) {
            float v = (lane < SEQ) ? wb[i][lane] : -INFINITY;
            float m = v;
            #pragma unroll
            for (int off = 32; off > 0; off >>= 1)
                m = fmaxf(m, __shfl_xor(m, off, 64));
            float e = (lane < SEQ) ? __expf(v - m) : 0.f;
            float ssum = e;
            #pragma unroll
            for (int off = 32; off > 0; off >>= 1)
                ssum += __shfl_xor(ssum, off, 64);
            wb[i][lane] = e / ssum;
        }
    }
    __syncthreads();

    // ---- weighted = attn @ v  (vs rows are the K dim) -> xs (x dead)
    gemm64<0, 0>(wb, vs, xs, nullptr, 1.f, t);
    __syncthreads();

    // ---- h1 = relu(weighted W1^T + b1) -> qs
    load_wT(W1, wb, t);
    __syncthreads();
    gemm64<1, 0>(xs, wb, qs, b1, 1.f, t);
    __syncthreads();

    // ---- h2 = relu(h1 W2^T + b2) -> kt (as row-major now)
    load_wT(W2, wb, t);
    __syncthreads();
    gemm64<1, 0>(qs, wb, kt, b2, 1.f, t);
    __syncthreads();

    // ---- out[s] = h2[s][:] . W3 + b3   (wave 0, lane = s)
    if (t < 64) {
        float acc = 0.f;
        #pragma unroll
        for (int d = 0; d < DIM; d += 4) {
            float4 h4 = *(const float4*)&kt[t][d];
            acc = fmaf(h4.x, W3[d], acc);
            acc = fmaf(h4.y, W3[d + 1], acc);
            acc = fmaf(h4.z, W3[d + 2], acc);
            acc = fmaf(h4.w, W3[d + 3], acc);
        }
        if (t < SEQ) out[(size_t)bp * SEQ + t] = acc + b3[0];
    }
}

extern "C" void kernel_launch(void* const* d_in, const int* in_sizes, int n_in,
                              void* d_out, int out_size, void* d_ws, size_t ws_size,
                              hipStream_t stream) {
    const float* x  = (const float*)d_in[0];
    const float* Wq = (const float*)d_in[1];
    const float* bq = (const float*)d_in[2];
    const float* Wk = (const float*)d_in[3];
    const float* bk = (const float*)d_in[4];
    const float* Wv = (const float*)d_in[5];
    const float* bv = (const float*)d_in[6];
    const float* W1 = (const float*)d_in[7];
    const float* b1 = (const float*)d_in[8];
    const float* W2 = (const float*)d_in[9];
    const float* b2 = (const float*)d_in[10];
    const float* W3 = (const float*)d_in[11];
    const float* b3 = (const float*)d_in[12];
    float* out = (float*)d_out;

    const int nparts = 256 * 40;  // B * P
    fused_attn_mlp<<<nparts, 256, 0, stream>>>(x, Wq, bq, Wk, bk, Wv, bv,
                                               W1, b1, W2, b2, W3, b3, out);
}

// Round 2
// 110.513 us; speedup vs baseline: 11.0545x; 11.0545x over previous
//
#include <hip/hip_runtime.h>
#include <math.h>

// B=256, P=40, S=60, D=64. One WAVE per (b,p) part; 64-thread blocks; no barriers.
// All seven 64x64x64 GEMMs via mfma_f32_16x16x32_f16 (4x4 tiles x 2 K-steps).
// f16 operands, fp32 accumulation. q,k,h1,h2 computed transposed (W * x^T) so
// every LDS store is a contiguous half4 and every operand read is the same
// "A-style" fragment: elem = M[16*t + (lane&15)][32*ks + 8*(lane>>4) + i].
//
// Verified-layout assumptions (cdna4 guide):
//   C/D: d[j] -> row=(lane>>4)*4+j, col=lane&15   [measured m89/m91]
//   A:   row=lane&15, k=(lane>>4)*8+i ; B: col=lane&15, k=(lane>>4)*8+i

typedef _Float16 half8 __attribute__((ext_vector_type(8)));
typedef _Float16 half4v __attribute__((ext_vector_type(4)));
typedef float f4 __attribute__((ext_vector_type(4)));

#define STR 72  // LDS row stride in halves: 144B = 9*16B -> 16B-aligned rows, 2-way banks
#define MFMA16(a, b, c) __builtin_amdgcn_mfma_f32_16x16x32_f16((a), (b), (c), 0, 0, 0)

__global__ __launch_bounds__(256) void prep_weights(
    const float* __restrict__ Wq, const float* __restrict__ Wk,
    const float* __restrict__ Wv, const float* __restrict__ W1,
    const float* __restrict__ W2, _Float16* __restrict__ wsH) {
    int i = blockIdx.x * 256 + threadIdx.x;  // 0..20479
    int m = i >> 12, r = i & 4095;
    const float* s = (m == 0) ? Wq : (m == 1) ? Wk : (m == 2) ? Wv : (m == 3) ? W1 : W2;
    wsH[i] = (_Float16)s[r];
}

__device__ __forceinline__ half8 cvt8(const float* __restrict__ p) {
    f4 a = *(const f4*)p, b = *(const f4*)(p + 4);
    half8 h;
    h[0] = (_Float16)a[0]; h[1] = (_Float16)a[1]; h[2] = (_Float16)a[2]; h[3] = (_Float16)a[3];
    h[4] = (_Float16)b[0]; h[5] = (_Float16)b[1]; h[6] = (_Float16)b[2]; h[7] = (_Float16)b[3];
    return h;
}

// Store D (4x4 tiles) into buf[16*nt+lo][16*mt+4*g .. +3] (contiguous half4).
// BIASMODE: 0 = bias indexed by D-row (brow[mt][j]), 1 = bias by D-col (bcol[nt]), 2 = none.
template <int BIASMODE, bool RELU>
__device__ __forceinline__ void storeT(_Float16 (*__restrict__ buf)[STR],
                                       const f4 acc[4][4], const f4* brow,
                                       const float* bcol, int lo, int g) {
    #pragma unroll
    for (int mt = 0; mt < 4; ++mt)
        #pragma unroll
        for (int nt = 0; nt < 4; ++nt) {
            half4v h;
            #pragma unroll
            for (int j = 0; j < 4; ++j) {
                float v = acc[mt][nt][j];
                if (BIASMODE == 0) v += brow[mt][j];
                if (BIASMODE == 1) v += bcol[nt];
                if (RELU) v = fmaxf(v, 0.f);
                h[j] = (_Float16)v;
            }
            *(half4v*)&buf[16 * nt + lo][16 * mt + 4 * g] = h;
        }
}

// AEXPR/BEXPR use variables t, ks.
#define GEMM(AEXPR, BEXPR)                                                   \
    do {                                                                     \
        _Pragma("unroll")                                                    \
        for (int mt = 0; mt < 4; ++mt)                                       \
            _Pragma("unroll")                                                \
            for (int nt = 0; nt < 4; ++nt) acc[mt][nt] = (f4){0.f, 0.f, 0.f, 0.f}; \
        _Pragma("unroll")                                                    \
        for (int ks = 0; ks < 2; ++ks) {                                     \
            half8 afr[4], bfr[4];                                            \
            _Pragma("unroll")                                                \
            for (int t = 0; t < 4; ++t) { afr[t] = (AEXPR); bfr[t] = (BEXPR); } \
            _Pragma("unroll")                                                \
            for (int mt = 0; mt < 4; ++mt)                                   \
                _Pragma("unroll")                                            \
                for (int nt = 0; nt < 4; ++nt)                               \
                    acc[mt][nt] = MFMA16(afr[mt], bfr[nt], acc[mt][nt]);     \
        }                                                                    \
    } while (0)

#define LDSA(buf) (*(const half8*)&buf[16 * t + lo][32 * ks + 8 * g])
#define WFR(widx) (*(const half8*)&wH[(widx) * 4096 + (16 * t + lo) * 64 + 32 * ks + 8 * g])

__global__ __launch_bounds__(64) void fused_f16(
    const float* __restrict__ x, const _Float16* __restrict__ wH,
    const float* __restrict__ bq, const float* __restrict__ bk,
    const float* __restrict__ bv, const float* __restrict__ b1,
    const float* __restrict__ b2, const float* __restrict__ W3,
    const float* __restrict__ b3, float* __restrict__ out) {
    __shared__ __align__(16) _Float16 sA[64][STR];  // q[s][e]   -> P[s][c]
    __shared__ __align__(16) _Float16 sB[64][STR];  // k[c][d]   -> weighted[s][d]
    __shared__ __align__(16) _Float16 sC[64][STR];  // vT[d][c]  -> h1[s][e]

    const int l = threadIdx.x;
    const int lo = l & 15, g = l >> 4;
    const int bp = blockIdx.x;
    const float* __restrict__ xp = x + (size_t)bp * (60 * 64);

    // ---- x fragments in registers (rows >= 60 zeroed). Used as A (v) and B (qT,kT).
    half8 xf[4][2];
    #pragma unroll
    for (int t = 0; t < 4; ++t) {
        int r = 16 * t + lo;
        #pragma unroll
        for (int ks = 0; ks < 2; ++ks) {
            if (r < 60) xf[t][ks] = cvt8(xp + r * 64 + ks * 32 + g * 8);
            else { half8 z = {}; xf[t][ks] = z; }
        }
    }

    f4 acc[4][4];
    f4 brow[4];
    float bcol[4];

    // ---- qT = Wq * xT ; store q[s][e] row-major into sA
    GEMM(WFR(0), xf[t][ks]);
    #pragma unroll
    for (int mt = 0; mt < 4; ++mt) brow[mt] = *(const f4*)&bq[16 * mt + 4 * g];
    storeT<0, false>(sA, acc, brow, nullptr, lo, g);

    // ---- kT = Wk * xT ; store k[c][d] row-major into sB
    GEMM(WFR(1), xf[t][ks]);
    #pragma unroll
    for (int mt = 0; mt < 4; ++mt) brow[mt] = *(const f4*)&bk[16 * mt + 4 * g];
    storeT<0, false>(sB, acc, brow, nullptr, lo, g);

    // ---- v = x * WvT ; store vT[d][c] into sC (D-col indexed rows)
    GEMM(xf[t][ks], WFR(2));
    #pragma unroll
    for (int nt = 0; nt < 4; ++nt) bcol[nt] = bv[16 * nt + lo];
    storeT<1, false>(sC, acc, nullptr, bcol, lo, g);

    // ---- scoresT[c][s] = sum_d k[c][d] q[s][d]
    GEMM(LDSA(sB), LDSA(sA));

    // ---- softmax over c (rows of scoresT = in-lane mt,j + cross-g), scale 1/8
    #pragma unroll
    for (int nt = 0; nt < 4; ++nt) {
        float mx = -3e38f;
        #pragma unroll
        for (int mt = 0; mt < 4; ++mt)
            #pragma unroll
            for (int j = 0; j < 4; ++j)
                if (!(mt == 3 && g == 3)) mx = fmaxf(mx, acc[mt][nt][j]);
        mx = fmaxf(mx, __shfl_xor(mx, 16));
        mx = fmaxf(mx, __shfl_xor(mx, 32));
        float sum = 0.f;
        #pragma unroll
        for (int mt = 0; mt < 4; ++mt)
            #pragma unroll
            for (int j = 0; j < 4; ++j) {
                float e = (mt == 3 && g == 3) ? 0.f
                          : __expf((acc[mt][nt][j] - mx) * 0.125f);
                acc[mt][nt][j] = e;
                sum += e;
            }
        sum += __shfl_xor(sum, 16);
        sum += __shfl_xor(sum, 32);
        float inv = 1.f / sum;
        #pragma unroll
        for (int mt = 0; mt < 4; ++mt)
            #pragma unroll
            for (int j = 0; j < 4; ++j) acc[mt][nt][j] *= inv;
    }
    // store P[s][c] row-major into sA (q dead)
    storeT<2, false>(sA, acc, nullptr, nullptr, lo, g);

    // ---- weightedT[d][s] = sum_c vT[d][c] P[s][c] ; store weighted[s][d] into sB
    GEMM(LDSA(sC), LDSA(sA));
    storeT<2, false>(sB, acc, nullptr, nullptr, lo, g);

    // ---- h1T = W1 * weightedT ; relu + b1 ; store h1[s][e] into sC
    GEMM(WFR(3), LDSA(sB));
    #pragma unroll
    for (int mt = 0; mt < 4; ++mt) brow[mt] = *(const f4*)&b1[16 * mt + 4 * g];
    storeT<0, true>(sC, acc, brow, nullptr, lo, g);

    // ---- h2T = W2 * h1T ; relu + b2 in regs
    GEMM(WFR(4), LDSA(sC));
    #pragma unroll
    for (int mt = 0; mt < 4; ++mt) brow[mt] = *(const f4*)&b2[16 * mt + 4 * g];
    #pragma unroll
    for (int mt = 0; mt < 4; ++mt)
        #pragma unroll
        for (int nt = 0; nt < 4; ++nt)
            #pragma unroll
            for (int j = 0; j < 4; ++j)
                acc[mt][nt][j] = fmaxf(acc[mt][nt][j] + brow[mt][j], 0.f);

    // ---- out[s] = sum_e h2T[e][s] * W3[e] + b3
    f4 w3r[4];
    #pragma unroll
    for (int mt = 0; mt < 4; ++mt) w3r[mt] = *(const f4*)&W3[16 * mt + 4 * g];
    float b3v = b3[0];
    #pragma unroll
    for (int nt = 0; nt < 4; ++nt) {
        float sres = 0.f;
        #pragma unroll
        for (int mt = 0; mt < 4; ++mt)
            #pragma unroll
            for (int j = 0; j < 4; ++j) sres += acc[mt][nt][j] * w3r[mt][j];
        sres += __shfl_xor(sres, 16);
        sres += __shfl_xor(sres, 32);
        if (g == 0) {
            int s = 16 * nt + lo;
            if (s < 60) out[(size_t)bp * 60 + s] = sres + b3v;
        }
    }
}

extern "C" void kernel_launch(void* const* d_in, const int* in_sizes, int n_in,
                              void* d_out, int out_size, void* d_ws, size_t ws_size,
                              hipStream_t stream) {
    const float* x  = (const float*)d_in[0];
    const float* Wq = (const float*)d_in[1];
    const float* bq = (const float*)d_in[2];
    const float* Wk = (const float*)d_in[3];
    const float* bk = (const float*)d_in[4];
    const float* Wv = (const float*)d_in[5];
    const float* bv = (const float*)d_in[6];
    const float* W1 = (const float*)d_in[7];
    const float* b1 = (const float*)d_in[8];
    const float* W2 = (const float*)d_in[9];
    const float* b2 = (const float*)d_in[10];
    const float* W3 = (const float*)d_in[11];
    const float* b3 = (const float*)d_in[12];
    float* out = (float*)d_out;
    _Float16* wsH = (_Float16*)d_ws;  // 5 * 4096 halves = 40 KB

    prep_weights<<<80, 256, 0, stream>>>(Wq, Wk, Wv, W1, W2, wsH);
    fused_f16<<<256 * 40, 64, 0, stream>>>(x, wsH, bq, bk, bv, b1, b2, W3, b3,
                                           (float*)d_out);
}

// Round 3
// 91.966 us; speedup vs baseline: 13.2838x; 1.2017x over previous
//
#include <hip/hip_runtime.h>
#include <math.h>

// B=256, P=40, S=60, D=64. One WAVE per (b,p) part; 64-thread blocks; no barriers.
// All seven 64x64x64 GEMMs via mfma_f32_16x16x32_f16 (4x4 tiles x 2 K-steps).
// f16 operands, fp32 accumulation. q,k,h1,h2 computed transposed (W * x^T) so
// every LDS store is a contiguous half4 and every operand read is the same
// "A-style" fragment: elem = M[16*t + (lane&15)][32*ks + 8*(lane>>4) + i].
//
// Round-3 changes (occupancy was 13%, latency-bound):
//  - 2 LDS buffers (18.4 KB) instead of 3 -> 8 blocks/CU (2 waves/SIMD).
//    Buffer reuse relies on same-wave in-order LDS (read-before-overwrite).
//  - Wq/Wk/Wv fragments prefetched to registers at wave start + all 16 x-loads
//    issued up front: ~30 KB outstanding per wave for memory-level parallelism.
//
// Verified-layout assumptions (cdna4 guide):
//   C/D: d[j] -> row=(lane>>4)*4+j, col=lane&15   [measured m89/m91]
//   A:   row=lane&15, k=(lane>>4)*8+i ; B: col=lane&15, k=(lane>>4)*8+i

typedef _Float16 half8 __attribute__((ext_vector_type(8)));
typedef _Float16 half4v __attribute__((ext_vector_type(4)));
typedef float f4 __attribute__((ext_vector_type(4)));

#define STR 72  // LDS row stride in halves: 144B = 9*16B -> 16B-aligned rows, 2-way banks
#define MFMA16(a, b, c) __builtin_amdgcn_mfma_f32_16x16x32_f16((a), (b), (c), 0, 0, 0)

__global__ __launch_bounds__(256) void prep_weights(
    const float* __restrict__ Wq, const float* __restrict__ Wk,
    const float* __restrict__ Wv, const float* __restrict__ W1,
    const float* __restrict__ W2, _Float16* __restrict__ wsH) {
    int i = blockIdx.x * 256 + threadIdx.x;  // 0..20479
    int m = i >> 12, r = i & 4095;
    const float* s = (m == 0) ? Wq : (m == 1) ? Wk : (m == 2) ? Wv : (m == 3) ? W1 : W2;
    wsH[i] = (_Float16)s[r];
}

__device__ __forceinline__ half8 cvt8(const float* __restrict__ p) {
    f4 a = *(const f4*)p, b = *(const f4*)(p + 4);
    half8 h;
    h[0] = (_Float16)a[0]; h[1] = (_Float16)a[1]; h[2] = (_Float16)a[2]; h[3] = (_Float16)a[3];
    h[4] = (_Float16)b[0]; h[5] = (_Float16)b[1]; h[6] = (_Float16)b[2]; h[7] = (_Float16)b[3];
    return h;
}

// Store D (4x4 tiles) into buf[16*nt+lo][16*mt+4*g .. +3] (contiguous half4).
// BIASMODE: 0 = bias indexed by D-row (brow[mt][j]), 1 = bias by D-col (bcol[nt]), 2 = none.
template <int BIASMODE, bool RELU>
__device__ __forceinline__ void storeT(_Float16 (*__restrict__ buf)[STR],
                                       const f4 acc[4][4], const f4* brow,
                                       const float* bcol, int lo, int g) {
    #pragma unroll
    for (int mt = 0; mt < 4; ++mt)
        #pragma unroll
        for (int nt = 0; nt < 4; ++nt) {
            half4v h;
            #pragma unroll
            for (int j = 0; j < 4; ++j) {
                float v = acc[mt][nt][j];
                if (BIASMODE == 0) v += brow[mt][j];
                if (BIASMODE == 1) v += bcol[nt];
                if (RELU) v = fmaxf(v, 0.f);
                h[j] = (_Float16)v;
            }
            *(half4v*)&buf[16 * nt + lo][16 * mt + 4 * g] = h;
        }
}

// AEXPR/BEXPR use variables t, ks.
#define GEMM(AEXPR, BEXPR)                                                   \
    do {                                                                     \
        _Pragma("unroll")                                                    \
        for (int mt = 0; mt < 4; ++mt)                                       \
            _Pragma("unroll")                                                \
            for (int nt = 0; nt < 4; ++nt) acc[mt][nt] = (f4){0.f, 0.f, 0.f, 0.f}; \
        _Pragma("unroll")                                                    \
        for (int ks = 0; ks < 2; ++ks) {                                     \
            half8 afr[4], bfr[4];                                            \
            _Pragma("unroll")                                                \
            for (int t = 0; t < 4; ++t) { afr[t] = (AEXPR); bfr[t] = (BEXPR); } \
            _Pragma("unroll")                                                \
            for (int mt = 0; mt < 4; ++mt)                                   \
                _Pragma("unroll")                                            \
                for (int nt = 0; nt < 4; ++nt)                               \
                    acc[mt][nt] = MFMA16(afr[mt], bfr[nt], acc[mt][nt]);     \
        }                                                                    \
    } while (0)

#define LDSA(buf) (*(const half8*)&buf[16 * t + lo][32 * ks + 8 * g])
#define WFR(widx) (*(const half8*)&wH[(widx) * 4096 + (16 * t + lo) * 64 + 32 * ks + 8 * g])

__global__ __launch_bounds__(64, 2) void fused_f16(
    const float* __restrict__ x, const _Float16* __restrict__ wH,
    const float* __restrict__ bq, const float* __restrict__ bk,
    const float* __restrict__ bv, const float* __restrict__ b1,
    const float* __restrict__ b2, const float* __restrict__ W3,
    const float* __restrict__ b3, float* __restrict__ out) {
    // 2 buffers x 64x72 halves = 18432 B -> 8 blocks/CU.
    __shared__ __align__(16) _Float16 s0[64][STR];  // q[s][e] -> P[s][c] -> weighted[s][d]
    __shared__ __align__(16) _Float16 s1[64][STR];  // k[c][d] -> vT[d][c] -> h1[s][e]

    const int l = threadIdx.x;
    const int lo = l & 15, g = l >> 4;
    const int bp = blockIdx.x;
    const float* __restrict__ xp = x + (size_t)bp * (60 * 64);

    // ---- x fragments in registers (rows >= 60 zeroed). Used as A (v) and B (qT,kT).
    half8 xf[4][2];
    #pragma unroll
    for (int t = 0; t < 4; ++t) {
        int r = 16 * t + lo;
        #pragma unroll
        for (int ks = 0; ks < 2; ++ks) {
            if (r < 60) xf[t][ks] = cvt8(xp + r * 64 + ks * 32 + g * 8);
            else { half8 z = {}; xf[t][ks] = z; }
        }
    }

    // ---- prefetch Wq/Wk/Wv fragments into registers (48 VGPR; occupancy is
    // LDS-capped at 2 waves/SIMD so VGPR up to 256 is free). W1/W2 load at use.
    half8 wq[4][2], wk[4][2], wv[4][2];
    #pragma unroll
    for (int t = 0; t < 4; ++t)
        #pragma unroll
        for (int ks = 0; ks < 2; ++ks) {
            wq[t][ks] = WFR(0);
            wk[t][ks] = WFR(1);
            wv[t][ks] = WFR(2);
        }

    f4 acc[4][4];
    f4 brow[4];
    float bcol[4];

    // ---- qT = Wq * xT ; store q[s][e] row-major into s0
    GEMM(wq[t][ks], xf[t][ks]);
    #pragma unroll
    for (int mt = 0; mt < 4; ++mt) brow[mt] = *(const f4*)&bq[16 * mt + 4 * g];
    storeT<0, false>(s0, acc, brow, nullptr, lo, g);

    // ---- kT = Wk * xT ; store k[c][d] row-major into s1
    GEMM(wk[t][ks], xf[t][ks]);
    #pragma unroll
    for (int mt = 0; mt < 4; ++mt) brow[mt] = *(const f4*)&bk[16 * mt + 4 * g];
    storeT<0, false>(s1, acc, brow, nullptr, lo, g);

    // ---- scoresT[c][s] = sum_d k[c][d] q[s][d]
    GEMM(LDSA(s1), LDSA(s0));

    // ---- softmax over c (rows of scoresT = in-lane mt,j + cross-g), scale 1/8
    #pragma unroll
    for (int nt = 0; nt < 4; ++nt) {
        float mx = -3e38f;
        #pragma unroll
        for (int mt = 0; mt < 4; ++mt)
            #pragma unroll
            for (int j = 0; j < 4; ++j)
                if (!(mt == 3 && g == 3)) mx = fmaxf(mx, acc[mt][nt][j]);
        mx = fmaxf(mx, __shfl_xor(mx, 16));
        mx = fmaxf(mx, __shfl_xor(mx, 32));
        float sum = 0.f;
        #pragma unroll
        for (int mt = 0; mt < 4; ++mt)
            #pragma unroll
            for (int j = 0; j < 4; ++j) {
                float e = (mt == 3 && g == 3) ? 0.f
                          : __expf((acc[mt][nt][j] - mx) * 0.125f);
                acc[mt][nt][j] = e;
                sum += e;
            }
        sum += __shfl_xor(sum, 16);
        sum += __shfl_xor(sum, 32);
        float inv = 1.f / sum;
        #pragma unroll
        for (int mt = 0; mt < 4; ++mt)
            #pragma unroll
            for (int j = 0; j < 4; ++j) acc[mt][nt][j] *= inv;
    }
    // store P[s][c] row-major into s0 (q dead; same-wave in-order LDS => safe)
    storeT<2, false>(s0, acc, nullptr, nullptr, lo, g);

    // ---- v = x * WvT ; store vT[d][c] into s1 (k dead)
    GEMM(xf[t][ks], wv[t][ks]);
    #pragma unroll
    for (int nt = 0; nt < 4; ++nt) bcol[nt] = bv[16 * nt + lo];
    storeT<1, false>(s1, acc, nullptr, bcol, lo, g);

    // ---- weightedT[d][s] = sum_c vT[d][c] P[s][c] ; store weighted[s][d] into s0
    GEMM(LDSA(s1), LDSA(s0));
    storeT<2, false>(s0, acc, nullptr, nullptr, lo, g);

    // ---- h1T = W1 * weightedT ; relu + b1 ; store h1[s][e] into s1
    GEMM(WFR(3), LDSA(s0));
    #pragma unroll
    for (int mt = 0; mt < 4; ++mt) brow[mt] = *(const f4*)&b1[16 * mt + 4 * g];
    storeT<0, true>(s1, acc, brow, nullptr, lo, g);

    // ---- h2T = W2 * h1T ; relu + b2 in regs
    GEMM(WFR(4), LDSA(s1));
    #pragma unroll
    for (int mt = 0; mt < 4; ++mt) brow[mt] = *(const f4*)&b2[16 * mt + 4 * g];
    #pragma unroll
    for (int mt = 0; mt < 4; ++mt)
        #pragma unroll
        for (int nt = 0; nt < 4; ++nt)
            #pragma unroll
            for (int j = 0; j < 4; ++j)
                acc[mt][nt][j] = fmaxf(acc[mt][nt][j] + brow[mt][j], 0.f);

    // ---- out[s] = sum_e h2T[e][s] * W3[e] + b3
    f4 w3r[4];
    #pragma unroll
    for (int mt = 0; mt < 4; ++mt) w3r[mt] = *(const f4*)&W3[16 * mt + 4 * g];
    float b3v = b3[0];
    #pragma unroll
    for (int nt = 0; nt < 4; ++nt) {
        float sres = 0.f;
        #pragma unroll
        for (int mt = 0; mt < 4; ++mt)
            #pragma unroll
            for (int j = 0; j < 4; ++j) sres += acc[mt][nt][j] * w3r[mt][j];
        sres += __shfl_xor(sres, 16);
        sres += __shfl_xor(sres, 32);
        if (g == 0) {
            int s = 16 * nt + lo;
            if (s < 60) out[(size_t)bp * 60 + s] = sres + b3v;
        }
    }
}

extern "C" void kernel_launch(void* const* d_in, const int* in_sizes, int n_in,
                              void* d_out, int out_size, void* d_ws, size_t ws_size,
                              hipStream_t stream) {
    const float* x  = (const float*)d_in[0];
    const float* Wq = (const float*)d_in[1];
    const float* bq = (const float*)d_in[2];
    const float* Wk = (const float*)d_in[3];
    const float* bk = (const float*)d_in[4];
    const float* Wv = (const float*)d_in[5];
    const float* bv = (const float*)d_in[6];
    const float* W1 = (const float*)d_in[7];
    const float* b1 = (const float*)d_in[8];
    const float* W2 = (const float*)d_in[9];
    const float* b2 = (const float*)d_in[10];
    const float* W3 = (const float*)d_in[11];
    const float* b3 = (const float*)d_in[12];
    _Float16* wsH = (_Float16*)d_ws;  // 5 * 4096 halves = 40 KB

    prep_weights<<<80, 256, 0, stream>>>(Wq, Wk, Wv, W1, W2, wsH);
    fused_f16<<<256 * 40, 64, 0, stream>>>(x, wsH, bq, bk, bv, b1, b2, W3, b3,
                                           (float*)d_out);
}